// Round 1
// baseline (168.849 us; speedup 1.0000x reference)
//
#include <hip/hip_runtime.h>
#include <stdint.h>

#define BB 8
#define SS 2048
#define DIN 768
#define DKV 64

typedef float f32x4 __attribute__((ext_vector_type(4)));
typedef __bf16 bf16x8 __attribute__((ext_vector_type(8)));

// ---------------------------------------------------------------------------
// Kernel 1: fused projections.  C[16384,64] = A[16384,768] @ W[64,768]^T + b
// which = 0:q (row-major out), 1:k (row-major out), 2:v (TRANSPOSED out)
// MFMA 16x16x32 bf16. A-frag: lane reads A[row=lo][k=8*hi+j]; B-frag:
// lane reads W[col=lo+16c][k=8*hi+j]. D: col=lo+16c, row=4*hi+r (m89 layout).
// ---------------------------------------------------------------------------
__global__ __launch_bounds__(256) void proj_kernel(
    const float* __restrict__ Aq, const float* __restrict__ Ak, const float* __restrict__ Av,
    const float* __restrict__ Wq, const float* __restrict__ bq,
    const float* __restrict__ Wk, const float* __restrict__ bk,
    const float* __restrict__ Wv, const float* __restrict__ bv,
    __bf16* __restrict__ q_ws, __bf16* __restrict__ k_ws, __bf16* __restrict__ vT_ws)
{
    const int which = blockIdx.y;
    const float* A; const float* W; const float* bias;
    if (which == 0)      { A = Aq; W = Wq; bias = bq; }
    else if (which == 1) { A = Ak; W = Wk; bias = bk; }
    else                 { A = Av; W = Wv; bias = bv; }

    const int wave = threadIdx.x >> 6;
    const int lane = threadIdx.x & 63;
    const int lo = lane & 15, hi = lane >> 4;
    const int row = blockIdx.x * 64 + wave * 16 + lo;   // A row for A-frag

    f32x4 acc[4] = {};   // col chunks c: cols 16c+lo

    const float* arow = A + (size_t)row * DIN;
    for (int kb = 0; kb < DIN; kb += 32) {
        bf16x8 af;
        {
            f32x4 a0 = *(const f32x4*)(arow + kb + 8*hi);
            f32x4 a1 = *(const f32x4*)(arow + kb + 8*hi + 4);
            #pragma unroll
            for (int j = 0; j < 4; j++) { af[j] = (__bf16)a0[j]; af[4+j] = (__bf16)a1[j]; }
        }
        #pragma unroll
        for (int c = 0; c < 4; c++) {
            const float* wrow = W + (size_t)(lo + 16*c) * DIN + kb + 8*hi;
            f32x4 w0 = *(const f32x4*)(wrow);
            f32x4 w1 = *(const f32x4*)(wrow + 4);
            bf16x8 bfr;
            #pragma unroll
            for (int j = 0; j < 4; j++) { bfr[j] = (__bf16)w0[j]; bfr[4+j] = (__bf16)w1[j]; }
            acc[c] = __builtin_amdgcn_mfma_f32_16x16x32_bf16(af, bfr, acc[c], 0, 0, 0);
        }
    }

    const int orow_base = blockIdx.x * 64 + wave * 16 + 4 * hi;
    #pragma unroll
    for (int c = 0; c < 4; c++) {
        const int col = lo + 16 * c;
        const float bcol = bias[col];
        #pragma unroll
        for (int r = 0; r < 4; r++) {
            const int orow = orow_base + r;            // 0..16383
            const float val = acc[c][r] + bcol;
            const int b = orow >> 11;                  // / 2048
            const int s = orow & 2047;
            if (which == 0)      q_ws[((size_t)b * SS + s) * DKV + col] = (__bf16)val;
            else if (which == 1) k_ws[((size_t)b * SS + s) * DKV + col] = (__bf16)val;
            else                 vT_ws[((size_t)b * DKV + col) * SS + s] = (__bf16)val;
        }
    }
}

// ---------------------------------------------------------------------------
// Kernel 2: flash attention.  4 waves/block, 16 q-rows/wave, KVBLK=64.
// QK: A=Q[16x32d], B=K^T (lane reads k_ws[key=lo][d=8hi+j], contiguous).
// D: col=key=lo, row=qrow=4hi+r.  Online softmax in f32; l kept lane-partial.
// P bounced through per-wave LDS [16][72] to the MFMA-A layout for PV.
// PV: B from vT_ws[vd=lo+16c][key=8hi+j], contiguous.
// ---------------------------------------------------------------------------
__global__ __launch_bounds__(256) void attn_kernel(
    const __bf16* __restrict__ q_ws, const __bf16* __restrict__ k_ws,
    const __bf16* __restrict__ vT_ws, const int* __restrict__ mask,
    float* __restrict__ out)
{
    __shared__ int mask_lds[SS];                        // 8 KB
    __shared__ __align__(16) __bf16 p_lds[4][16][72];   // 9.2 KB, 144B row stride

    const int b = blockIdx.y;
    const int qblk = blockIdx.x;        // 64 q-rows per block
    const int wave = threadIdx.x >> 6;
    const int lane = threadIdx.x & 63;
    const int lo = lane & 15, hi = lane >> 4;

    for (int i = threadIdx.x; i < SS; i += 256) mask_lds[i] = mask[b * SS + i];
    __syncthreads();

    const int qbase = qblk * 64 + wave * 16;

    // Q A-frags, hoisted (2 d-chunks of 32)
    const __bf16* qp = q_ws + ((size_t)b * SS + qbase + lo) * DKV;
    bf16x8 qf0 = *(const bf16x8*)(qp + 8 * hi);
    bf16x8 qf1 = *(const bf16x8*)(qp + 32 + 8 * hi);

    f32x4 oacc[4] = {};                 // v-chunks c: cols 16c+lo, rows 4hi+r
    float m[4], l[4];
    #pragma unroll
    for (int r = 0; r < 4; r++) { m[r] = -1e30f; l[r] = 0.f; }

    for (int kv = 0; kv < SS; kv += 64) {
        // ---- QK^T for 64 keys: 4 key-subtiles x 2 d-chunks ----
        f32x4 sacc[4] = {};
        #pragma unroll
        for (int sub = 0; sub < 4; sub++) {
            const __bf16* kp = k_ws + ((size_t)b * SS + kv + sub * 16 + lo) * DKV;
            bf16x8 kf0 = *(const bf16x8*)(kp + 8 * hi);
            bf16x8 kf1 = *(const bf16x8*)(kp + 32 + 8 * hi);
            sacc[sub] = __builtin_amdgcn_mfma_f32_16x16x32_bf16(qf0, kf0, sacc[sub], 0, 0, 0);
            sacc[sub] = __builtin_amdgcn_mfma_f32_16x16x32_bf16(qf1, kf1, sacc[sub], 0, 0, 0);
        }

        // ---- scale + mask ----
        float s_val[4][4];
        #pragma unroll
        for (int sub = 0; sub < 4; sub++) {
            const int key = kv + sub * 16 + lo;
            const bool msk = (mask_lds[key] != 0);
            #pragma unroll
            for (int r = 0; r < 4; r++)
                s_val[sub][r] = msk ? -1e30f : sacc[sub][r] * 0.125f;
        }

        // ---- chunk row-max (reduce over 16 lo-lanes) ----
        float cm[4];
        #pragma unroll
        for (int r = 0; r < 4; r++) {
            float v0 = fmaxf(fmaxf(s_val[0][r], s_val[1][r]),
                             fmaxf(s_val[2][r], s_val[3][r]));
            v0 = fmaxf(v0, __shfl_xor(v0, 1));
            v0 = fmaxf(v0, __shfl_xor(v0, 2));
            v0 = fmaxf(v0, __shfl_xor(v0, 4));
            v0 = fmaxf(v0, __shfl_xor(v0, 8));
            cm[r] = v0;
        }

        // ---- online-softmax update ----
        #pragma unroll
        for (int r = 0; r < 4; r++) {
            const float mnew = fmaxf(m[r], cm[r]);
            const float alpha = __expf(m[r] - mnew);
            m[r] = mnew;
            l[r] *= alpha;
            #pragma unroll
            for (int c = 0; c < 4; c++) oacc[c][r] *= alpha;
        }

        // ---- P = exp(s - m); accumulate lane-partial l; bounce to LDS ----
        #pragma unroll
        for (int sub = 0; sub < 4; sub++) {
            #pragma unroll
            for (int r = 0; r < 4; r++) {
                const float p = __expf(s_val[sub][r] - m[r]);
                l[r] += p;
                p_lds[wave][4 * hi + r][sub * 16 + lo] = (__bf16)p;
            }
        }
        asm volatile("s_waitcnt lgkmcnt(0)" ::: "memory");

        // ---- PV: A-frags from LDS (q=lo rows), B from vT ----
        bf16x8 pa0 = *(const bf16x8*)&p_lds[wave][lo][8 * hi];
        bf16x8 pa1 = *(const bf16x8*)&p_lds[wave][lo][32 + 8 * hi];
        #pragma unroll
        for (int c = 0; c < 4; c++) {
            const __bf16* vp = vT_ws + ((size_t)b * DKV + 16 * c + lo) * SS + kv;
            bf16x8 vf0 = *(const bf16x8*)(vp + 8 * hi);
            bf16x8 vf1 = *(const bf16x8*)(vp + 32 + 8 * hi);
            oacc[c] = __builtin_amdgcn_mfma_f32_16x16x32_bf16(pa0, vf0, oacc[c], 0, 0, 0);
            oacc[c] = __builtin_amdgcn_mfma_f32_16x16x32_bf16(pa1, vf1, oacc[c], 0, 0, 0);
        }
    }

    // ---- final l reduction across lo-lanes, write out ----
    #pragma unroll
    for (int r = 0; r < 4; r++) {
        float lv = l[r];
        lv += __shfl_xor(lv, 1);
        lv += __shfl_xor(lv, 2);
        lv += __shfl_xor(lv, 4);
        lv += __shfl_xor(lv, 8);
        l[r] = lv;
    }
    float* op = out + ((size_t)b * SS + qbase) * DKV;
    #pragma unroll
    for (int r = 0; r < 4; r++) {
        const float inv = 1.0f / l[r];
        #pragma unroll
        for (int c = 0; c < 4; c++)
            op[(size_t)(4 * hi + r) * DKV + 16 * c + lo] = oacc[c][r] * inv;
    }
}

extern "C" void kernel_launch(void* const* d_in, const int* in_sizes, int n_in,
                              void* d_out, int out_size, void* d_ws, size_t ws_size,
                              hipStream_t stream)
{
    (void)in_sizes; (void)n_in; (void)out_size; (void)ws_size;
    const float* query = (const float*)d_in[0];
    const float* key_  = (const float*)d_in[1];
    const float* value = (const float*)d_in[2];
    const int*   mask  = (const int*)d_in[3];
    const float* Wq    = (const float*)d_in[4];
    const float* bq    = (const float*)d_in[5];
    const float* Wk    = (const float*)d_in[6];
    const float* bk    = (const float*)d_in[7];
    const float* Wv    = (const float*)d_in[8];
    const float* bv    = (const float*)d_in[9];
    float* out = (float*)d_out;

    __bf16* q_ws  = (__bf16*)d_ws;                       // 2 MB
    __bf16* k_ws  = q_ws + (size_t)BB * SS * DKV;        // 2 MB
    __bf16* vT_ws = k_ws + (size_t)BB * SS * DKV;        // 2 MB (transposed)

    proj_kernel<<<dim3(256, 3, 1), 256, 0, stream>>>(
        query, key_, value, Wq, bq, Wk, bk, Wv, bv, q_ws, k_ws, vT_ws);
    attn_kernel<<<dim3(32, 8, 1), 256, 0, stream>>>(
        q_ws, k_ws, vT_ws, mask, out);
}

// Round 2
// 120.175 us; speedup vs baseline: 1.4050x; 1.4050x over previous
//
#include <hip/hip_runtime.h>
#include <stdint.h>

#define BB 8
#define SS 2048
#define DIN 768
#define DKV 64
#define NCHUNK (DIN / 32)   // 24 k-chunks of 32

typedef float f32x4 __attribute__((ext_vector_type(4)));
typedef __bf16 bf16x8 __attribute__((ext_vector_type(8)));

// ---------------------------------------------------------------------------
// Kernel 0: pre-convert W (f32, [64,768]) to bf16 MFMA-B fragment layout.
// wf[m][kc][c][lane] : bf16x8, lane(lo,hi) = W[col=16c+lo][k=32kc+8hi+j].
// 3 matrices x 24 kc x 4 c x 64 lanes x 16B = 98 KB/matrix (L2-resident).
// ---------------------------------------------------------------------------
__global__ void wconv_kernel(const float* __restrict__ Wq,
                             const float* __restrict__ Wk,
                             const float* __restrict__ Wv,
                             __bf16* __restrict__ wf)
{
    const int m = blockIdx.y;
    const float* W = (m == 0) ? Wq : (m == 1) ? Wk : Wv;
    const int kc = blockIdx.x;              // 0..23
    const int t = threadIdx.x;              // c*64 + lane
    const int c = t >> 6, lane = t & 63;
    const int lo = lane & 15, hi = lane >> 4;
    const float* src = W + (size_t)(16 * c + lo) * DIN + 32 * kc + 8 * hi;
    bf16x8 v;
    #pragma unroll
    for (int j = 0; j < 8; j++) v[j] = (__bf16)src[j];
    *(bf16x8*)(wf + ((((size_t)m * NCHUNK + kc) * 4 + c) * 64 + lane) * 8) = v;
}

// ---------------------------------------------------------------------------
// Kernel 1: fused projections, 2-chunk-deep register-prefetched.
// C[16384,64] = A[16384,768] @ W^T + b.  which=0:q, 1:k, 2:v(transposed out).
// Per wave: 16 rows; A loads 32B/lane contiguous (row = 128B segments);
// W loads 16B/lane from pre-converted frags (L2-hot).
// ---------------------------------------------------------------------------
__global__ __launch_bounds__(256) void proj_kernel(
    const float* __restrict__ Aq, const float* __restrict__ Ak, const float* __restrict__ Av,
    const __bf16* __restrict__ wf,
    const float* __restrict__ bq, const float* __restrict__ bk, const float* __restrict__ bv,
    __bf16* __restrict__ q_ws, __bf16* __restrict__ k_ws, __bf16* __restrict__ vT_ws)
{
    const int which = blockIdx.y;
    const float* A; const float* bias;
    if (which == 0)      { A = Aq; bias = bq; }
    else if (which == 1) { A = Ak; bias = bk; }
    else                 { A = Av; bias = bv; }
    const __bf16* wfm = wf + (size_t)which * NCHUNK * 4 * 64 * 8;

    const int wave = threadIdx.x >> 6;
    const int lane = threadIdx.x & 63;
    const int lo = lane & 15, hi = lane >> 4;
    const int row = blockIdx.x * 64 + wave * 16 + lo;
    const float* arow = A + (size_t)row * DIN;

    // ---- stage loaders ----
    #define LOADA(kc, a0, a1)  do { \
        a0 = *(const f32x4*)(arow + 32 * (kc) + 8 * hi); \
        a1 = *(const f32x4*)(arow + 32 * (kc) + 8 * hi + 4); } while (0)
    #define LOADW(kc, w)  do { \
        const __bf16* p_ = wfm + (((size_t)(kc) * 4 * 64) + lane) * 8; \
        w[0] = *(const bf16x8*)(p_); \
        w[1] = *(const bf16x8*)(p_ + 64 * 8); \
        w[2] = *(const bf16x8*)(p_ + 128 * 8); \
        w[3] = *(const bf16x8*)(p_ + 192 * 8); } while (0)
    #define CVT_MFMA(a0, a1, w, acc)  do { \
        bf16x8 af_; \
        _Pragma("unroll") \
        for (int j_ = 0; j_ < 4; j_++) { af_[j_] = (__bf16)a0[j_]; af_[4 + j_] = (__bf16)a1[j_]; } \
        _Pragma("unroll") \
        for (int c_ = 0; c_ < 4; c_++) \
            acc[c_] = __builtin_amdgcn_mfma_f32_16x16x32_bf16(af_, w[c_], acc[c_], 0, 0, 0); \
    } while (0)

    f32x4 a0A, a1A, a0B, a1B;
    bf16x8 wA[4], wB[4];
    LOADA(0, a0A, a1A); LOADW(0, wA);
    LOADA(1, a0B, a1B); LOADW(1, wB);

    f32x4 acc[4] = {};

    #pragma unroll 1
    for (int kc = 0; kc < NCHUNK; kc += 2) {
        // prefetch kc+2 (clamped at tail -> harmless duplicate load)
        const int pkA = (kc + 2 < NCHUNK) ? kc + 2 : kc;
        f32x4 n0A, n1A; bf16x8 nwA[4];
        LOADA(pkA, n0A, n1A); LOADW(pkA, nwA);

        CVT_MFMA(a0A, a1A, wA, acc);

        // prefetch kc+3
        const int pkB = (kc + 3 < NCHUNK) ? kc + 3 : kc + 1;
        f32x4 n0B, n1B; bf16x8 nwB[4];
        LOADA(pkB, n0B, n1B); LOADW(pkB, nwB);

        CVT_MFMA(a0B, a1B, wB, acc);

        a0A = n0A; a1A = n1A; a0B = n0B; a1B = n1B;
        #pragma unroll
        for (int c = 0; c < 4; c++) { wA[c] = nwA[c]; wB[c] = nwB[c]; }
    }

    // ---- epilogue: D col=lo+16c, row=4hi+r ----
    const int orow_base = blockIdx.x * 64 + wave * 16 + 4 * hi;
    #pragma unroll
    for (int c = 0; c < 4; c++) {
        const int col = lo + 16 * c;
        const float bcol = bias[col];
        #pragma unroll
        for (int r = 0; r < 4; r++) {
            const int orow = orow_base + r;
            const float val = acc[c][r] + bcol;
            const int b = orow >> 11;
            const int s = orow & 2047;
            if (which == 0)      q_ws[((size_t)b * SS + s) * DKV + col] = (__bf16)val;
            else if (which == 1) k_ws[((size_t)b * SS + s) * DKV + col] = (__bf16)val;
            else                 vT_ws[((size_t)b * DKV + col) * SS + s] = (__bf16)val;
        }
    }
    #undef LOADA
    #undef LOADW
    #undef CVT_MFMA
}

// ---------------------------------------------------------------------------
// Kernel 2: flash attention (unchanged from round 1).
// ---------------------------------------------------------------------------
__global__ __launch_bounds__(256) void attn_kernel(
    const __bf16* __restrict__ q_ws, const __bf16* __restrict__ k_ws,
    const __bf16* __restrict__ vT_ws, const int* __restrict__ mask,
    float* __restrict__ out)
{
    __shared__ int mask_lds[SS];
    __shared__ __align__(16) __bf16 p_lds[4][16][72];

    const int b = blockIdx.y;
    const int qblk = blockIdx.x;
    const int wave = threadIdx.x >> 6;
    const int lane = threadIdx.x & 63;
    const int lo = lane & 15, hi = lane >> 4;

    for (int i = threadIdx.x; i < SS; i += 256) mask_lds[i] = mask[b * SS + i];
    __syncthreads();

    const int qbase = qblk * 64 + wave * 16;

    const __bf16* qp = q_ws + ((size_t)b * SS + qbase + lo) * DKV;
    bf16x8 qf0 = *(const bf16x8*)(qp + 8 * hi);
    bf16x8 qf1 = *(const bf16x8*)(qp + 32 + 8 * hi);

    f32x4 oacc[4] = {};
    float m[4], l[4];
    #pragma unroll
    for (int r = 0; r < 4; r++) { m[r] = -1e30f; l[r] = 0.f; }

    for (int kv = 0; kv < SS; kv += 64) {
        f32x4 sacc[4] = {};
        #pragma unroll
        for (int sub = 0; sub < 4; sub++) {
            const __bf16* kp = k_ws + ((size_t)b * SS + kv + sub * 16 + lo) * DKV;
            bf16x8 kf0 = *(const bf16x8*)(kp + 8 * hi);
            bf16x8 kf1 = *(const bf16x8*)(kp + 32 + 8 * hi);
            sacc[sub] = __builtin_amdgcn_mfma_f32_16x16x32_bf16(qf0, kf0, sacc[sub], 0, 0, 0);
            sacc[sub] = __builtin_amdgcn_mfma_f32_16x16x32_bf16(qf1, kf1, sacc[sub], 0, 0, 0);
        }

        float s_val[4][4];
        #pragma unroll
        for (int sub = 0; sub < 4; sub++) {
            const int key = kv + sub * 16 + lo;
            const bool msk = (mask_lds[key] != 0);
            #pragma unroll
            for (int r = 0; r < 4; r++)
                s_val[sub][r] = msk ? -1e30f : sacc[sub][r] * 0.125f;
        }

        float cm[4];
        #pragma unroll
        for (int r = 0; r < 4; r++) {
            float v0 = fmaxf(fmaxf(s_val[0][r], s_val[1][r]),
                             fmaxf(s_val[2][r], s_val[3][r]));
            v0 = fmaxf(v0, __shfl_xor(v0, 1));
            v0 = fmaxf(v0, __shfl_xor(v0, 2));
            v0 = fmaxf(v0, __shfl_xor(v0, 4));
            v0 = fmaxf(v0, __shfl_xor(v0, 8));
            cm[r] = v0;
        }

        #pragma unroll
        for (int r = 0; r < 4; r++) {
            const float mnew = fmaxf(m[r], cm[r]);
            const float alpha = __expf(m[r] - mnew);
            m[r] = mnew;
            l[r] *= alpha;
            #pragma unroll
            for (int c = 0; c < 4; c++) oacc[c][r] *= alpha;
        }

        #pragma unroll
        for (int sub = 0; sub < 4; sub++) {
            #pragma unroll
            for (int r = 0; r < 4; r++) {
                const float p = __expf(s_val[sub][r] - m[r]);
                l[r] += p;
                p_lds[wave][4 * hi + r][sub * 16 + lo] = (__bf16)p;
            }
        }
        asm volatile("s_waitcnt lgkmcnt(0)" ::: "memory");

        bf16x8 pa0 = *(const bf16x8*)&p_lds[wave][lo][8 * hi];
        bf16x8 pa1 = *(const bf16x8*)&p_lds[wave][lo][32 + 8 * hi];
        #pragma unroll
        for (int c = 0; c < 4; c++) {
            const __bf16* vp = vT_ws + ((size_t)b * DKV + 16 * c + lo) * SS + kv;
            bf16x8 vf0 = *(const bf16x8*)(vp + 8 * hi);
            bf16x8 vf1 = *(const bf16x8*)(vp + 32 + 8 * hi);
            oacc[c] = __builtin_amdgcn_mfma_f32_16x16x32_bf16(pa0, vf0, oacc[c], 0, 0, 0);
            oacc[c] = __builtin_amdgcn_mfma_f32_16x16x32_bf16(pa1, vf1, oacc[c], 0, 0, 0);
        }
    }

    #pragma unroll
    for (int r = 0; r < 4; r++) {
        float lv = l[r];
        lv += __shfl_xor(lv, 1);
        lv += __shfl_xor(lv, 2);
        lv += __shfl_xor(lv, 4);
        lv += __shfl_xor(lv, 8);
        l[r] = lv;
    }
    float* op = out + ((size_t)b * SS + qbase) * DKV;
    #pragma unroll
    for (int r = 0; r < 4; r++) {
        const float inv = 1.0f / l[r];
        #pragma unroll
        for (int c = 0; c < 4; c++)
            op[(size_t)(4 * hi + r) * DKV + 16 * c + lo] = oacc[c][r] * inv;
    }
}

extern "C" void kernel_launch(void* const* d_in, const int* in_sizes, int n_in,
                              void* d_out, int out_size, void* d_ws, size_t ws_size,
                              hipStream_t stream)
{
    (void)in_sizes; (void)n_in; (void)out_size; (void)ws_size;
    const float* query = (const float*)d_in[0];
    const float* key_  = (const float*)d_in[1];
    const float* value = (const float*)d_in[2];
    const int*   mask  = (const int*)d_in[3];
    const float* Wq    = (const float*)d_in[4];
    const float* bq    = (const float*)d_in[5];
    const float* Wk    = (const float*)d_in[6];
    const float* bk    = (const float*)d_in[7];
    const float* Wv    = (const float*)d_in[8];
    const float* bv    = (const float*)d_in[9];
    float* out = (float*)d_out;

    __bf16* q_ws  = (__bf16*)d_ws;                         // 2 MB
    __bf16* k_ws  = q_ws + (size_t)BB * SS * DKV;          // 2 MB
    __bf16* vT_ws = k_ws + (size_t)BB * SS * DKV;          // 2 MB (transposed)
    __bf16* wf    = vT_ws + (size_t)BB * SS * DKV;         // 3 x 98 KB frag-W

    wconv_kernel<<<dim3(NCHUNK, 3, 1), 256, 0, stream>>>(Wq, Wk, Wv, wf);
    proj_kernel<<<dim3(256, 3, 1), 256, 0, stream>>>(
        query, key_, value, wf, bq, bk, bv, q_ws, k_ws, vT_ws);
    attn_kernel<<<dim3(32, 8, 1), 256, 0, stream>>>(
        q_ws, k_ws, vT_ws, mask, out);
}